// Round 1
// 518.575 us; speedup vs baseline: 1.2031x; 1.2031x over previous
//
#include <hip/hip_runtime.h>
#include <hip/hip_bf16.h>
#include <stdint.h>

// y[b,s,o] = sum_i x[b,s,i] * (w[o,i]*mask[o,i]) + bias[o]
// M = 8192 (B*S), N = 4096 (D_OUT), K = 4096 (D_IN). fp32 in/out, bf16 MFMA.
#define M_DIM 8192
#define N_DIM 4096
#define K_DIM 4096

// ---- 8-phase 256x256 GEMM geometry (m201 template) ----
#define BM 256
#define BN 256
#define BK 64
#define NT (K_DIM / BK)   // 64 K-tiles

typedef __attribute__((ext_vector_type(8))) __bf16 bf16x8;
typedef __attribute__((ext_vector_type(4))) float floatx4;

// ---------- fp32 -> bf16 (RNE) packing helpers ----------
__device__ inline unsigned f2b(float f) {
    union { float f; unsigned u; } v; v.f = f;
    return (v.u + 0x7FFFu + ((v.u >> 16) & 1u)) >> 16;   // RNE; inputs finite
}
__device__ inline unsigned pk2(float lo, float hi) {
    return (f2b(lo) & 0xFFFFu) | (f2b(hi) << 16);
}

// Async global->LDS, 16B/lane. Low 32 bits of flat shared ptr == LDS offset.
__device__ inline void async_load16(const void* g, void* l) {
    __builtin_amdgcn_global_load_lds(
        (const __attribute__((address_space(1))) unsigned int*)(unsigned long long)g,
        (__attribute__((address_space(3))) unsigned int*)(unsigned int)(unsigned long long)l,
        16, 0, 0);
}

#define SFENCE() asm volatile("" ::: "memory")

// ---------- Pass 1a: x fp32 -> bf16 (contiguous 16B load / 8B store) ----------
__global__ __launch_bounds__(256)
void cvt_x_kernel(const float4* __restrict__ in, uint2* __restrict__ out, int n4) {
    int i = blockIdx.x * blockDim.x + threadIdx.x;
    const int stride = gridDim.x * blockDim.x;
    for (; i < n4; i += stride) {
        float4 a = in[i];
        uint2 o; o.x = pk2(a.x, a.y); o.y = pk2(a.z, a.w);
        out[i] = o;
    }
}

// ---------- Pass 1b: wb = bf16(w * mask) ----------
__global__ __launch_bounds__(256)
void cvt_w_kernel(const float4* __restrict__ w, const float4* __restrict__ m,
                  uint2* __restrict__ out, int n4) {
    int i = blockIdx.x * blockDim.x + threadIdx.x;
    const int stride = gridDim.x * blockDim.x;
    for (; i < n4; i += stride) {
        float4 a = w[i], q = m[i];
        uint2 o; o.x = pk2(a.x * q.x, a.y * q.y); o.y = pk2(a.z * q.z, a.w * q.w);
        out[i] = o;
    }
}

// ---------- Pass 2: 256x256 8-phase GEMM, C = A @ B^T + bias ----------
// 8 waves (2M x 4N), per-wave 128x64 output = 8x4 frags of 16x16.
// LDS: 2 dbuf x {A,B} x 2 halves x [128][64] bf16 = 128 KiB.
// Per K-tile: 4 phases x {ds_read subtile | stage 1 half-tile | bar |
// lgkmcnt(0) | setprio(1) 16xMFMA setprio(0) | bar}; vmcnt(6) once per tile.
// Stage stream runs 1.5 tiles ahead: P1 -> A*r1(s+1), P2 -> A*r0(s+2),
// P3 -> B0(s+2), P4 -> B1(s+2).  vmcnt(6) at P4 guarantees all of tile s+1.
// LDS swizzle: 16B chunk c of row r lives at chunk c^(r&7); global source is
// pre-swizzled so global_load_lds dests stay linear (rule 21).
__global__ __launch_bounds__(512, 2)
void gemm_8phase(const __hip_bfloat16* __restrict__ A,
                 const __hip_bfloat16* __restrict__ B,
                 const float* __restrict__ bias,
                 float* __restrict__ C) {
    __shared__ __hip_bfloat16 As[2][2][128][64];   // [buf][half][row][col] 64 KiB
    __shared__ __hip_bfloat16 Bs[2][2][128][64];   // 64 KiB

    const int t    = threadIdx.x;
    const int lane = t & 63;
    const int wave = t >> 6;        // 0..7
    const int wm   = wave >> 2;     // 0..1 : M-half of tile
    const int wn   = wave & 3;      // 0..3 : N-quarter of tile
    const int lm   = lane & 15;
    const int h4   = lane >> 4;     // 0..3

    // XCD-aware bijective swizzle: 512 wgs = 8 XCDs x 64
    const int wg = (blockIdx.x & 7) * 64 + (blockIdx.x >> 3);
    const int m0 = (wg >> 4) * BM;  // 32 m-tiles
    const int n0 = (wg & 15) * BN;  // 16 n-tiles

    // Staging map: thread t stages 16B chunk (t&7) of row (t>>3) of a 64-row
    // unit. Source chunk is inverse-swizzled.
    const int srow = t >> 3;            // 0..63
    const int schk = t & 7;
    const int sx   = schk ^ (srow & 7); // source chunk (involution)

    const __hip_bfloat16* gA[2][2];
    const __hip_bfloat16* gB[2][2];
#pragma unroll
    for (int h = 0; h < 2; h++)
#pragma unroll
        for (int r = 0; r < 2; r++) {
            gA[h][r] = A + (size_t)(m0 + h * 128 + r * 64 + srow) * K_DIM + sx * 8;
            gB[h][r] = B + (size_t)(n0 + h * 128 + r * 64 + srow) * K_DIM + sx * 8;
        }

#define STAGE_A(b, h, r, tt) \
    async_load16(gA[h][r] + (tt) * BK, &As[b][h][(r) * 64 + srow][schk * 8])
#define STAGE_B(b, h, r, tt) \
    async_load16(gB[h][r] + (tt) * BK, &Bs[b][h][(r) * 64 + srow][schk * 8])

    // Frag reads: row-in-half = i*16+lm, chunk = kk*4+h4, swizzled by row&7.
    const int cs0 = ((h4)     ^ (lm & 7)) * 8;   // kk=0 element offset
    const int cs1 = ((4 + h4) ^ (lm & 7)) * 8;   // kk=1

#define LDA(b, i, kk) \
    (*(const bf16x8*)&As[b][wm][(i) * 16 + lm][(kk) ? cs1 : cs0])
#define LDB(b, j, kk) \
    (*(const bf16x8*)&Bs[b][wn >> 1][(wn & 1) * 64 + (j) * 16 + lm][(kk) ? cs1 : cs0])

    floatx4 acc[8][4] = {};
    bf16x8 af[4][2], bf01[2][2], bf23[2][2];

    // ---- prologue: 14 stages in steady-state stream order ----
    STAGE_A(0, 0, 0, 0); STAGE_A(0, 1, 0, 0);
    STAGE_B(0, 0, 0, 0); STAGE_B(0, 0, 1, 0);
    STAGE_B(0, 1, 0, 0); STAGE_B(0, 1, 1, 0);
    STAGE_A(0, 0, 1, 0); STAGE_A(0, 1, 1, 0);
    STAGE_A(1, 0, 0, 1); STAGE_A(1, 1, 0, 1);
    STAGE_B(1, 0, 0, 1); STAGE_B(1, 0, 1, 1);
    STAGE_B(1, 1, 0, 1); STAGE_B(1, 1, 1, 1);
    asm volatile("s_waitcnt vmcnt(6)" ::: "memory");  // tile0 landed, 6 in flight
    __builtin_amdgcn_s_barrier();
    SFENCE();

    for (int s = 0; s < NT; ++s) {
        const int b  = s & 1;
        const int nb = b ^ 1;

        // ---------------- P1: Q00 (i=0..3, j=0..1) ----------------
#pragma unroll
        for (int i = 0; i < 4; i++) { af[i][0] = LDA(b, i, 0); af[i][1] = LDA(b, i, 1); }
#pragma unroll
        for (int j = 0; j < 2; j++) { bf01[j][0] = LDB(b, j, 0); bf01[j][1] = LDB(b, j, 1); }
        if (s + 1 < NT) { STAGE_A(nb, 0, 1, s + 1); STAGE_A(nb, 1, 1, s + 1); }
        asm volatile("s_waitcnt lgkmcnt(8)" ::: "memory");   // 12 ds_reads issued
        SFENCE(); __builtin_amdgcn_s_barrier();
        asm volatile("s_waitcnt lgkmcnt(0)" ::: "memory");
        __builtin_amdgcn_s_setprio(1);
#pragma unroll
        for (int i = 0; i < 4; i++)
#pragma unroll
            for (int j = 0; j < 2; j++)
#pragma unroll
                for (int kk = 0; kk < 2; kk++)
                    acc[i][j] = __builtin_amdgcn_mfma_f32_16x16x32_bf16(
                        af[i][kk], bf01[j][kk], acc[i][j], 0, 0, 0);
        __builtin_amdgcn_s_setprio(0);
        SFENCE(); __builtin_amdgcn_s_barrier(); SFENCE();

        // ---------------- P2: Q01 (i=0..3, j=2..3) ----------------
#pragma unroll
        for (int j = 0; j < 2; j++) { bf23[j][0] = LDB(b, 2 + j, 0); bf23[j][1] = LDB(b, 2 + j, 1); }
        if (s + 2 < NT) { STAGE_A(b, 0, 0, s + 2); STAGE_A(b, 1, 0, s + 2); }
        SFENCE(); __builtin_amdgcn_s_barrier();
        asm volatile("s_waitcnt lgkmcnt(0)" ::: "memory");
        __builtin_amdgcn_s_setprio(1);
#pragma unroll
        for (int i = 0; i < 4; i++)
#pragma unroll
            for (int j = 0; j < 2; j++)
#pragma unroll
                for (int kk = 0; kk < 2; kk++)
                    acc[i][2 + j] = __builtin_amdgcn_mfma_f32_16x16x32_bf16(
                        af[i][kk], bf23[j][kk], acc[i][2 + j], 0, 0, 0);
        __builtin_amdgcn_s_setprio(0);
        SFENCE(); __builtin_amdgcn_s_barrier(); SFENCE();

        // ---------------- P3: Q10 (i=4..7, j=0..1) ----------------
#pragma unroll
        for (int i = 0; i < 4; i++) { af[i][0] = LDA(b, 4 + i, 0); af[i][1] = LDA(b, 4 + i, 1); }
        if (s + 2 < NT) { STAGE_B(b, 0, 0, s + 2); STAGE_B(b, 0, 1, s + 2); }
        SFENCE(); __builtin_amdgcn_s_barrier();
        asm volatile("s_waitcnt lgkmcnt(0)" ::: "memory");
        __builtin_amdgcn_s_setprio(1);
#pragma unroll
        for (int i = 0; i < 4; i++)
#pragma unroll
            for (int j = 0; j < 2; j++)
#pragma unroll
                for (int kk = 0; kk < 2; kk++)
                    acc[4 + i][j] = __builtin_amdgcn_mfma_f32_16x16x32_bf16(
                        af[i][kk], bf01[j][kk], acc[4 + i][j], 0, 0, 0);
        __builtin_amdgcn_s_setprio(0);
        SFENCE(); __builtin_amdgcn_s_barrier(); SFENCE();

        // ---------------- P4: Q11 (i=4..7, j=2..3) ----------------
        if (s + 2 < NT) { STAGE_B(b, 1, 0, s + 2); STAGE_B(b, 1, 1, s + 2); }
        __builtin_amdgcn_s_setprio(1);
#pragma unroll
        for (int i = 0; i < 4; i++)
#pragma unroll
            for (int j = 0; j < 2; j++)
#pragma unroll
                for (int kk = 0; kk < 2; kk++)
                    acc[4 + i][2 + j] = __builtin_amdgcn_mfma_f32_16x16x32_bf16(
                        af[i][kk], bf23[j][kk], acc[4 + i][2 + j], 0, 0, 0);
        __builtin_amdgcn_s_setprio(0);
        if (s + 2 < NT) asm volatile("s_waitcnt vmcnt(6)" ::: "memory");
        else            asm volatile("s_waitcnt vmcnt(0)" ::: "memory");
        SFENCE(); __builtin_amdgcn_s_barrier(); SFENCE();
    }

    // ---- epilogue: C/D layout col = lane&15, row = (lane>>4)*4 + reg ----
    float bv[4];
#pragma unroll
    for (int j = 0; j < 4; j++)
        bv[j] = bias[n0 + wn * 64 + j * 16 + lm];
    const int row_base = m0 + wm * 128 + h4 * 4;
    const int col_base = n0 + wn * 64 + lm;
#pragma unroll
    for (int i = 0; i < 8; i++)
#pragma unroll
        for (int j = 0; j < 4; j++) {
            const int col = col_base + j * 16;
#pragma unroll
            for (int r = 0; r < 4; r++)
                C[(size_t)(row_base + i * 16 + r) * N_DIM + col] =
                    acc[i][j][r] + bv[j];
        }
}

extern "C" void kernel_launch(void* const* d_in, const int* in_sizes, int n_in,
                              void* d_out, int out_size, void* d_ws, size_t ws_size,
                              hipStream_t stream) {
    const float* x    = (const float*)d_in[0];   // [4,2048,4096] fp32
    const float* w    = (const float*)d_in[1];   // [4096,4096] fp32
    const float* bias = (const float*)d_in[2];   // [4096] fp32
    const float* mask = (const float*)d_in[3];   // [4096,4096] fp32
    float* out = (float*)d_out;                  // [8192,4096] fp32

    __hip_bfloat16* xb = (__hip_bfloat16*)d_ws;                    // 64 MiB
    __hip_bfloat16* wb = xb + (size_t)M_DIM * K_DIM;               // 32 MiB

    cvt_x_kernel<<<dim3(2048), dim3(256), 0, stream>>>(
        (const float4*)x, (uint2*)xb, M_DIM * K_DIM / 4);
    cvt_w_kernel<<<dim3(2048), dim3(256), 0, stream>>>(
        (const float4*)w, (const float4*)mask, (uint2*)wb, N_DIM * K_DIM / 4);
    gemm_8phase<<<dim3(512), dim3(512), 0, stream>>>(xb, wb, bias, out);
}